// Round 3
// baseline (238.651 us; speedup 1.0000x reference)
//
#include <hip/hip_runtime.h>
#include <math.h>

// Problem constants
#define BATCH 256
#define IC    1152   // 32*6*6 input capsule positions
#define DD    8
#define OO    10
#define EE    16
#define BTILE 64     // batches per block
#define NBT   4      // BATCH / BTILE
#define NT    640    // OO * BTILE threads per block (10 waves)
#define CHUNK 9      // ijk positions per block (finer split -> 2 blocks/CU)
#define NCHUNK 128   // IC / CHUNK
#define SJ    3      // ijk per round (one barrier per round)
#define ROUNDS (CHUNK / SJ)   // 3

// pass kernel: recompute u_hat on the fly.
//  - W is read via wave-uniform scalar loads (o is constant per wave ->
//    readfirstlane forces s_load; FMA consumes W from SGPRs). No W in LDS.
//  - x is double-buffered in LDS, register-prefetched one round ahead.
//  - routing logits exchanged through LDS once per round (SJ=3 ijk share
//    one barrier; u kept in registers across the barrier).
//  - launch_bounds(640,5): 5 waves/EU min -> 2 blocks/CU, VGPR cap 102.
__global__ __launch_bounds__(NT, 5) void caps_pass_kernel(
    const float* __restrict__ x,       // [256][1152][8]
    const float* __restrict__ W,       // [1152][10][8][16]
    const float* __restrict__ V,       // [256][10][16] accumulated v
    float* __restrict__ s_part,        // [NCHUNK][256][10][16]
    int first)
{
    __shared__ float x_lds[2][SJ][DD][BTILE];   // d-major: conflict-free b32 reads
    __shared__ float logit_lds[2][SJ][NT];

    const int tid = threadIdx.x;
    const int o   = tid >> 6;        // wave id 0..9
    const int bl  = tid & 63;
    const int o_u = __builtin_amdgcn_readfirstlane(o);   // wave-uniform o
    const int b   = blockIdx.y * BTILE + bl;
    const int ijk0 = blockIdx.x * CHUNK;

    // per-thread copy of V[b,o,:]
    float vreg[EE];
    if (first) {
        #pragma unroll
        for (int e = 0; e < EE; ++e) vreg[e] = 0.f;
    } else {
        const float4* vp = reinterpret_cast<const float4*>(V + ((size_t)b * OO + o) * EE);
        #pragma unroll
        for (int q = 0; q < 4; ++q) {
            float4 t = vp[q];
            vreg[q * 4 + 0] = t.x; vreg[q * 4 + 1] = t.y;
            vreg[q * 4 + 2] = t.z; vreg[q * 4 + 3] = t.w;
        }
    }

    float sacc[EE];
    #pragma unroll
    for (int e = 0; e < EE; ++e) sacc[e] = 0.f;

    // x loader mapping: threads 0..383 each fetch one float4 per round
    const bool loader = tid < SJ * BTILE * 2;   // 384
    const int ls = tid >> 7;         // 0..2  (which ijk of the round)
    const int lr = tid & 127;
    const int lb = lr >> 1;          // 0..63 (batch within tile)
    const int lq = lr & 1;           // 0..1  (which half of the 8 d's)
    const float* xbase = x + (size_t)(blockIdx.y * BTILE + lb) * (IC * DD) + lq * 4;

    // prologue: load round 0, write to buffer 0
    float4 xpre = make_float4(0.f, 0.f, 0.f, 0.f);
    if (loader) xpre = *reinterpret_cast<const float4*>(xbase + (size_t)(ijk0 + ls) * DD);
    if (loader) {
        x_lds[0][ls][lq * 4 + 0][lb] = xpre.x;
        x_lds[0][ls][lq * 4 + 1][lb] = xpre.y;
        x_lds[0][ls][lq * 4 + 2][lb] = xpre.z;
        x_lds[0][ls][lq * 4 + 3][lb] = xpre.w;
    }
    __syncthreads();

    int p = 0;
    for (int r = 0; r < ROUNDS; ++r) {
        // C: issue global prefetch for round r+1 (latency hidden by compute)
        if (r + 1 < ROUNDS && loader)
            xpre = *reinterpret_cast<const float4*>(
                xbase + (size_t)(ijk0 + (r + 1) * SJ + ls) * DD);

        // A: compute u for SJ ijks; write logits
        float u[SJ][EE];
        float lgr[SJ];
        #pragma unroll
        for (int s = 0; s < SJ; ++s) {
            const int ijk = ijk0 + r * SJ + s;
            const float* wp = W + (size_t)ijk * (OO * DD * EE) + o_u * (DD * EE);
            float xr[DD];
            #pragma unroll
            for (int d = 0; d < DD; ++d) xr[d] = x_lds[p][s][d][bl];
            #pragma unroll
            for (int e = 0; e < EE; ++e) u[s][e] = 0.f;
            #pragma unroll
            for (int d = 0; d < DD; ++d) {
                #pragma unroll
                for (int e = 0; e < EE; ++e)
                    u[s][e] = fmaf(xr[d], wp[d * EE + e], u[s][e]);  // W from SGPR
            }
            if (!first) {
                float lg = 0.f;
                #pragma unroll
                for (int e = 0; e < EE; ++e) lg += u[s][e] * vreg[e];
                lgr[s] = lg;
                logit_lds[p][s][tid] = lg;
            }
        }

        // B: write prefetched x into the other buffer
        if (r + 1 < ROUNDS && loader) {
            x_lds[p ^ 1][ls][lq * 4 + 0][lb] = xpre.x;
            x_lds[p ^ 1][ls][lq * 4 + 1][lb] = xpre.y;
            x_lds[p ^ 1][ls][lq * 4 + 2][lb] = xpre.z;
            x_lds[p ^ 1][ls][lq * 4 + 3][lb] = xpre.w;
        }

        // D: single barrier per round (covers x swap + logit visibility)
        __syncthreads();

        // E: softmax over o, accumulate s
        if (first) {
            #pragma unroll
            for (int s = 0; s < SJ; ++s)
                #pragma unroll
                for (int e = 0; e < EE; ++e) sacc[e] += 0.1f * u[s][e];
        } else {
            #pragma unroll
            for (int s = 0; s < SJ; ++s) {
                float m = -1e30f;
                #pragma unroll
                for (int oo = 0; oo < OO; ++oo)
                    m = fmaxf(m, logit_lds[p][s][oo * 64 + bl]);
                float den = 0.f;
                #pragma unroll
                for (int oo = 0; oo < OO; ++oo)
                    den += __expf(logit_lds[p][s][oo * 64 + bl] - m);
                float c = __expf(lgr[s] - m) / den;
                #pragma unroll
                for (int e = 0; e < EE; ++e) sacc[e] += c * u[s][e];
            }
        }
        p ^= 1;
    }

    // write partial s for this chunk
    float* sp = s_part + (((size_t)blockIdx.x * BATCH + b) * OO + o) * EE;
    #pragma unroll
    for (int q = 0; q < 4; ++q) {
        float4 t;
        t.x = sacc[q * 4 + 0]; t.y = sacc[q * 4 + 1];
        t.z = sacc[q * 4 + 2]; t.w = sacc[q * 4 + 3];
        reinterpret_cast<float4*>(sp)[q] = t;
    }
}

// squash kernel: reduce partial s over chunks, squash, update V (or write out).
__global__ __launch_bounds__(256) void caps_squash_kernel(
    const float* __restrict__ s_part,  // [NCHUNK][256][10][16]
    float* __restrict__ V,             // [256][10][16]
    float* __restrict__ out,           // [256][10][16]
    int accum, int last)
{
    const int g = blockIdx.x * 256 + threadIdx.x;   // < 40960
    float s = 0.f;
    #pragma unroll 8
    for (int ch = 0; ch < NCHUNK; ++ch)
        s += s_part[(size_t)ch * (BATCH * OO * EE) + g];

    // squared norm over the 16-element e axis (lanes g..g+15 share (b,o))
    float sq = s * s;
    #pragma unroll
    for (int m = 1; m < 16; m <<= 1) sq += __shfl_xor(sq, m, 16);

    float scale = sq / (1.f + sq) / (sqrtf(sq) + 1e-6f);
    float v = scale * s;

    if (last)       out[g] = v;
    else if (accum) V[g]  += v;
    else            V[g]   = v;
}

extern "C" void kernel_launch(void* const* d_in, const int* in_sizes, int n_in,
                              void* d_out, int out_size, void* d_ws, size_t ws_size,
                              hipStream_t stream) {
    const float* x = (const float*)d_in[0];   // [256,32,6,6,8]
    const float* W = (const float*)d_in[1];   // [1,32,6,6,10,8,16]
    float* out = (float*)d_out;               // [256,10,16]

    float* s_part = (float*)d_ws;                                   // NCHUNK*40960 floats
    float* V      = s_part + (size_t)NCHUNK * BATCH * OO * EE;      // 40960 floats

    dim3 grid(NCHUNK, NBT), blk(NT);
    const int sq_blocks = (BATCH * OO * EE) / 256;   // 160

    // iteration 1: b=0 -> c uniform 0.1; v1 -> V
    caps_pass_kernel<<<grid, blk, 0, stream>>>(x, W, V, s_part, 1);
    caps_squash_kernel<<<sq_blocks, 256, 0, stream>>>(s_part, V, out, 0, 0);
    // iteration 2: logits = dot(u_hat, v1); V += v2
    caps_pass_kernel<<<grid, blk, 0, stream>>>(x, W, V, s_part, 0);
    caps_squash_kernel<<<sq_blocks, 256, 0, stream>>>(s_part, V, out, 1, 0);
    // iteration 3 (final): logits = dot(u_hat, v1+v2); output v3
    caps_pass_kernel<<<grid, blk, 0, stream>>>(x, W, V, s_part, 0);
    caps_squash_kernel<<<sq_blocks, 256, 0, stream>>>(s_part, V, out, 0, 1);
}

// Round 4
// 178.528 us; speedup vs baseline: 1.3368x; 1.3368x over previous
//
#include <hip/hip_runtime.h>
#include <math.h>

// Problem constants
#define BATCH 256
#define IC    1152   // 32*6*6 input capsule positions
#define DD    8
#define OO    10
#define EE    16
#define BTILE 64     // batches per block
#define NBT   4      // BATCH / BTILE
#define NT    640    // OO * BTILE threads per block (10 waves)
#define CHUNK 9      // ijk positions per block (finer split -> 2 blocks/CU)
#define NCHUNK 128   // IC / CHUNK
#define SJ    3      // ijk per round (one barrier per round)
#define ROUNDS (CHUNK / SJ)   // 3

// pass kernel: recompute u_hat on the fly.
//  - W is read via wave-uniform scalar loads (o is constant per wave ->
//    readfirstlane forces s_load; FMA consumes W from SGPRs). No W in LDS.
//  - x is double-buffered in LDS, register-prefetched one round ahead.
//  - routing logits exchanged through LDS once per round (SJ=3 ijk share
//    one barrier; u kept in registers across the barrier).
//  NOTE: no min-waves launch_bounds arg — R3 showed capping VGPRs to fit
//  5 waves/EU spills u[3][16]/sacc/vreg to scratch (VGPR 48, +70 MB HBM
//  traffic/pass, 62 us). At natural ~84 VGPR, 2 blocks/CU fit anyway.
__global__ __launch_bounds__(NT) void caps_pass_kernel(
    const float* __restrict__ x,       // [256][1152][8]
    const float* __restrict__ W,       // [1152][10][8][16]
    const float* __restrict__ V,       // [256][10][16] accumulated v
    float* __restrict__ s_part,        // [NCHUNK][256][10][16]
    int first)
{
    __shared__ float x_lds[2][SJ][DD][BTILE];   // d-major: conflict-free b32 reads
    __shared__ float logit_lds[2][SJ][NT];

    const int tid = threadIdx.x;
    const int o   = tid >> 6;        // wave id 0..9
    const int bl  = tid & 63;
    const int o_u = __builtin_amdgcn_readfirstlane(o);   // wave-uniform o
    const int b   = blockIdx.y * BTILE + bl;
    const int ijk0 = blockIdx.x * CHUNK;

    // per-thread copy of V[b,o,:]
    float vreg[EE];
    if (first) {
        #pragma unroll
        for (int e = 0; e < EE; ++e) vreg[e] = 0.f;
    } else {
        const float4* vp = reinterpret_cast<const float4*>(V + ((size_t)b * OO + o) * EE);
        #pragma unroll
        for (int q = 0; q < 4; ++q) {
            float4 t = vp[q];
            vreg[q * 4 + 0] = t.x; vreg[q * 4 + 1] = t.y;
            vreg[q * 4 + 2] = t.z; vreg[q * 4 + 3] = t.w;
        }
    }

    float sacc[EE];
    #pragma unroll
    for (int e = 0; e < EE; ++e) sacc[e] = 0.f;

    // x loader mapping: threads 0..383 each fetch one float4 per round
    const bool loader = tid < SJ * BTILE * 2;   // 384
    const int ls = tid >> 7;         // 0..2  (which ijk of the round)
    const int lr = tid & 127;
    const int lb = lr >> 1;          // 0..63 (batch within tile)
    const int lq = lr & 1;           // 0..1  (which half of the 8 d's)
    const float* xbase = x + (size_t)(blockIdx.y * BTILE + lb) * (IC * DD) + lq * 4;

    // prologue: load round 0, write to buffer 0
    float4 xpre = make_float4(0.f, 0.f, 0.f, 0.f);
    if (loader) xpre = *reinterpret_cast<const float4*>(xbase + (size_t)(ijk0 + ls) * DD);
    if (loader) {
        x_lds[0][ls][lq * 4 + 0][lb] = xpre.x;
        x_lds[0][ls][lq * 4 + 1][lb] = xpre.y;
        x_lds[0][ls][lq * 4 + 2][lb] = xpre.z;
        x_lds[0][ls][lq * 4 + 3][lb] = xpre.w;
    }
    __syncthreads();

    int p = 0;
    for (int r = 0; r < ROUNDS; ++r) {
        // C: issue global prefetch for round r+1 (latency hidden by compute)
        if (r + 1 < ROUNDS && loader)
            xpre = *reinterpret_cast<const float4*>(
                xbase + (size_t)(ijk0 + (r + 1) * SJ + ls) * DD);

        // A: compute u for SJ ijks; write logits
        float u[SJ][EE];
        float lgr[SJ];
        #pragma unroll
        for (int s = 0; s < SJ; ++s) {
            const int ijk = ijk0 + r * SJ + s;
            const float* wp = W + (size_t)ijk * (OO * DD * EE) + o_u * (DD * EE);
            float xr[DD];
            #pragma unroll
            for (int d = 0; d < DD; ++d) xr[d] = x_lds[p][s][d][bl];
            #pragma unroll
            for (int e = 0; e < EE; ++e) u[s][e] = 0.f;
            #pragma unroll
            for (int d = 0; d < DD; ++d) {
                #pragma unroll
                for (int e = 0; e < EE; ++e)
                    u[s][e] = fmaf(xr[d], wp[d * EE + e], u[s][e]);  // W from SGPR
            }
            if (!first) {
                float lg = 0.f;
                #pragma unroll
                for (int e = 0; e < EE; ++e) lg += u[s][e] * vreg[e];
                lgr[s] = lg;
                logit_lds[p][s][tid] = lg;
            }
        }

        // B: write prefetched x into the other buffer
        if (r + 1 < ROUNDS && loader) {
            x_lds[p ^ 1][ls][lq * 4 + 0][lb] = xpre.x;
            x_lds[p ^ 1][ls][lq * 4 + 1][lb] = xpre.y;
            x_lds[p ^ 1][ls][lq * 4 + 2][lb] = xpre.z;
            x_lds[p ^ 1][ls][lq * 4 + 3][lb] = xpre.w;
        }

        // D: single barrier per round (covers x swap + logit visibility)
        __syncthreads();

        // E: softmax over o, accumulate s
        if (first) {
            #pragma unroll
            for (int s = 0; s < SJ; ++s)
                #pragma unroll
                for (int e = 0; e < EE; ++e) sacc[e] += 0.1f * u[s][e];
        } else {
            #pragma unroll
            for (int s = 0; s < SJ; ++s) {
                float m = -1e30f;
                #pragma unroll
                for (int oo = 0; oo < OO; ++oo)
                    m = fmaxf(m, logit_lds[p][s][oo * 64 + bl]);
                float den = 0.f;
                #pragma unroll
                for (int oo = 0; oo < OO; ++oo)
                    den += __expf(logit_lds[p][s][oo * 64 + bl] - m);
                float c = __expf(lgr[s] - m) / den;
                #pragma unroll
                for (int e = 0; e < EE; ++e) sacc[e] += c * u[s][e];
            }
        }
        p ^= 1;
    }

    // write partial s for this chunk
    float* sp = s_part + (((size_t)blockIdx.x * BATCH + b) * OO + o) * EE;
    #pragma unroll
    for (int q = 0; q < 4; ++q) {
        float4 t;
        t.x = sacc[q * 4 + 0]; t.y = sacc[q * 4 + 1];
        t.z = sacc[q * 4 + 2]; t.w = sacc[q * 4 + 3];
        reinterpret_cast<float4*>(sp)[q] = t;
    }
}

// squash kernel: reduce partial s over chunks, squash, update V (or write out).
__global__ __launch_bounds__(256) void caps_squash_kernel(
    const float* __restrict__ s_part,  // [NCHUNK][256][10][16]
    float* __restrict__ V,             // [256][10][16]
    float* __restrict__ out,           // [256][10][16]
    int accum, int last)
{
    const int g = blockIdx.x * 256 + threadIdx.x;   // < 40960
    float s = 0.f;
    #pragma unroll 8
    for (int ch = 0; ch < NCHUNK; ++ch)
        s += s_part[(size_t)ch * (BATCH * OO * EE) + g];

    // squared norm over the 16-element e axis (lanes g..g+15 share (b,o))
    float sq = s * s;
    #pragma unroll
    for (int m = 1; m < 16; m <<= 1) sq += __shfl_xor(sq, m, 16);

    float scale = sq / (1.f + sq) / (sqrtf(sq) + 1e-6f);
    float v = scale * s;

    if (last)       out[g] = v;
    else if (accum) V[g]  += v;
    else            V[g]   = v;
}

extern "C" void kernel_launch(void* const* d_in, const int* in_sizes, int n_in,
                              void* d_out, int out_size, void* d_ws, size_t ws_size,
                              hipStream_t stream) {
    const float* x = (const float*)d_in[0];   // [256,32,6,6,8]
    const float* W = (const float*)d_in[1];   // [1,32,6,6,10,8,16]
    float* out = (float*)d_out;               // [256,10,16]

    float* s_part = (float*)d_ws;                                   // NCHUNK*40960 floats
    float* V      = s_part + (size_t)NCHUNK * BATCH * OO * EE;      // 40960 floats

    dim3 grid(NCHUNK, NBT), blk(NT);
    const int sq_blocks = (BATCH * OO * EE) / 256;   // 160

    // iteration 1: b=0 -> c uniform 0.1; v1 -> V
    caps_pass_kernel<<<grid, blk, 0, stream>>>(x, W, V, s_part, 1);
    caps_squash_kernel<<<sq_blocks, 256, 0, stream>>>(s_part, V, out, 0, 0);
    // iteration 2: logits = dot(u_hat, v1); V += v2
    caps_pass_kernel<<<grid, blk, 0, stream>>>(x, W, V, s_part, 0);
    caps_squash_kernel<<<sq_blocks, 256, 0, stream>>>(s_part, V, out, 1, 0);
    // iteration 3 (final): logits = dot(u_hat, v1+v2); output v3
    caps_pass_kernel<<<grid, blk, 0, stream>>>(x, W, V, s_part, 0);
    caps_squash_kernel<<<sq_blocks, 256, 0, stream>>>(s_part, V, out, 0, 1);
}

// Round 5
// 173.588 us; speedup vs baseline: 1.3748x; 1.0285x over previous
//
#include <hip/hip_runtime.h>
#include <math.h>

// Problem constants
#define BATCH 256
#define IC    1152   // 32*6*6 input capsule positions
#define DD    8
#define OO    10
#define EE    16
#define BTILE 128    // batches per block (2 per thread -> W reuse x2)
#define NBT   2      // BATCH / BTILE
#define NT    640    // OO * 64 threads per block (10 waves, wave = one o)
#define CHUNK 9      // ijk positions per block
#define NCHUNK 128   // IC / CHUNK  -> grid 256 blocks

// pass kernel: recompute u_hat on the fly.
//  - W via wave-uniform scalar loads (o uniform per wave); each W float
//    feeds TWO fmacs (batches bl and bl+64) -> scalar traffic halved,
//    2x independent FMA chains per wave vs 1-batch version.
//  - x double-buffered in LDS, register-prefetched one ijk ahead.
//  - one barrier per ijk (covers x swap + logit exchange).
//  - NO min-waves launch_bounds: R3 showed reg caps cause catastrophic
//    scratch spills (VGPR 48, +70MB HBM/pass). Natural alloc ~130 VGPR.
__global__ __launch_bounds__(NT) void caps_pass_kernel(
    const float* __restrict__ x,       // [256][1152][8]
    const float* __restrict__ W,       // [1152][10][8][16]
    const float* __restrict__ V,       // [256][10][16] accumulated v
    float* __restrict__ s_part,        // [NCHUNK][256][10][16]
    int first)
{
    __shared__ float x_lds[2][DD][BTILE];        // 8 KB, d-major: conflict-free
    __shared__ float logit_lds[2][2][OO][64];    // 10 KB: [buf][half][o][bl]

    const int tid = threadIdx.x;
    const int o   = tid >> 6;        // wave id 0..9
    const int bl  = tid & 63;
    const int o_u = __builtin_amdgcn_readfirstlane(o);
    const int b0  = blockIdx.y * BTILE + bl;
    const int b1  = b0 + 64;
    const int ijk0 = blockIdx.x * CHUNK;

    // per-thread V[b,o,:] for both batches
    float v0[EE], v1[EE];
    if (first) {
        #pragma unroll
        for (int e = 0; e < EE; ++e) { v0[e] = 0.f; v1[e] = 0.f; }
    } else {
        const float4* vp0 = reinterpret_cast<const float4*>(V + ((size_t)b0 * OO + o) * EE);
        const float4* vp1 = reinterpret_cast<const float4*>(V + ((size_t)b1 * OO + o) * EE);
        #pragma unroll
        for (int q = 0; q < 4; ++q) {
            float4 t0 = vp0[q], t1 = vp1[q];
            v0[q*4+0]=t0.x; v0[q*4+1]=t0.y; v0[q*4+2]=t0.z; v0[q*4+3]=t0.w;
            v1[q*4+0]=t1.x; v1[q*4+1]=t1.y; v1[q*4+2]=t1.z; v1[q*4+3]=t1.w;
        }
    }

    float s0[EE], s1[EE];
    #pragma unroll
    for (int e = 0; e < EE; ++e) { s0[e] = 0.f; s1[e] = 0.f; }

    // x loader mapping: threads 0..255 each fetch one float4 per ijk
    const bool loader = tid < BTILE * 2;   // 256
    const int lb = tid >> 1;               // 0..127
    const int lq = tid & 1;                // which half of the 8 d's
    const float* xbase = x + (size_t)(blockIdx.y * BTILE + lb) * (IC * DD) + lq * 4;

    // prologue: load ijk0 into buffer 0
    float4 xpre = make_float4(0.f, 0.f, 0.f, 0.f);
    if (loader) {
        xpre = *reinterpret_cast<const float4*>(xbase + (size_t)ijk0 * DD);
        x_lds[0][lq*4+0][lb] = xpre.x;
        x_lds[0][lq*4+1][lb] = xpre.y;
        x_lds[0][lq*4+2][lb] = xpre.z;
        x_lds[0][lq*4+3][lb] = xpre.w;
    }
    __syncthreads();

    int p = 0;
    for (int r = 0; r < CHUNK; ++r) {
        const int ijk = ijk0 + r;

        // prefetch next ijk's x into registers (latency hidden by compute)
        if (r + 1 < CHUNK && loader)
            xpre = *reinterpret_cast<const float4*>(xbase + (size_t)(ijk + 1) * DD);

        // u for both batches; W consumed from SGPRs, each float used twice
        const float* wp = W + (size_t)ijk * (OO * DD * EE) + o_u * (DD * EE);
        float u0[EE], u1[EE];
        #pragma unroll
        for (int e = 0; e < EE; ++e) { u0[e] = 0.f; u1[e] = 0.f; }
        #pragma unroll
        for (int d = 0; d < DD; ++d) {
            float x0 = x_lds[p][d][bl];
            float x1 = x_lds[p][d][bl + 64];
            #pragma unroll
            for (int e = 0; e < EE; ++e) {
                float w = wp[d * EE + e];
                u0[e] = fmaf(x0, w, u0[e]);
                u1[e] = fmaf(x1, w, u1[e]);
            }
        }

        float lg0 = 0.f, lg1 = 0.f;
        if (!first) {
            #pragma unroll
            for (int e = 0; e < EE; ++e) {
                lg0 = fmaf(u0[e], v0[e], lg0);
                lg1 = fmaf(u1[e], v1[e], lg1);
            }
            logit_lds[p][0][o][bl] = lg0;
            logit_lds[p][1][o][bl] = lg1;
        }

        // write prefetched x into the other buffer
        if (r + 1 < CHUNK && loader) {
            x_lds[p^1][lq*4+0][lb] = xpre.x;
            x_lds[p^1][lq*4+1][lb] = xpre.y;
            x_lds[p^1][lq*4+2][lb] = xpre.z;
            x_lds[p^1][lq*4+3][lb] = xpre.w;
        }

        // single barrier per ijk: x swap + logit visibility
        __syncthreads();

        float c0, c1;
        if (first) {
            c0 = 0.1f; c1 = 0.1f;      // softmax of zero logits over O=10
        } else {
            // read each logit once into registers, then 2-pass softmax
            float l0[OO], l1[OO];
            #pragma unroll
            for (int oo = 0; oo < OO; ++oo) {
                l0[oo] = logit_lds[p][0][oo][bl];
                l1[oo] = logit_lds[p][1][oo][bl];
            }
            float m0 = -1e30f, m1 = -1e30f;
            #pragma unroll
            for (int oo = 0; oo < OO; ++oo) {
                m0 = fmaxf(m0, l0[oo]);
                m1 = fmaxf(m1, l1[oo]);
            }
            float d0 = 0.f, d1 = 0.f;
            #pragma unroll
            for (int oo = 0; oo < OO; ++oo) {
                d0 += __expf(l0[oo] - m0);
                d1 += __expf(l1[oo] - m1);
            }
            c0 = __expf(lg0 - m0) / d0;
            c1 = __expf(lg1 - m1) / d1;
        }

        #pragma unroll
        for (int e = 0; e < EE; ++e) {
            s0[e] = fmaf(c0, u0[e], s0[e]);
            s1[e] = fmaf(c1, u1[e], s1[e]);
        }
        p ^= 1;
    }

    // write partial s for this chunk, both batch halves
    float* sp0 = s_part + (((size_t)blockIdx.x * BATCH + b0) * OO + o) * EE;
    float* sp1 = s_part + (((size_t)blockIdx.x * BATCH + b1) * OO + o) * EE;
    #pragma unroll
    for (int q = 0; q < 4; ++q) {
        float4 t0, t1;
        t0.x = s0[q*4+0]; t0.y = s0[q*4+1]; t0.z = s0[q*4+2]; t0.w = s0[q*4+3];
        t1.x = s1[q*4+0]; t1.y = s1[q*4+1]; t1.z = s1[q*4+2]; t1.w = s1[q*4+3];
        reinterpret_cast<float4*>(sp0)[q] = t0;
        reinterpret_cast<float4*>(sp1)[q] = t1;
    }
}

// squash kernel: reduce partial s over chunks, squash, update V (or write out).
__global__ __launch_bounds__(256) void caps_squash_kernel(
    const float* __restrict__ s_part,  // [NCHUNK][256][10][16]
    float* __restrict__ V,             // [256][10][16]
    float* __restrict__ out,           // [256][10][16]
    int accum, int last)
{
    const int g = blockIdx.x * 256 + threadIdx.x;   // < 40960
    float s = 0.f;
    #pragma unroll 8
    for (int ch = 0; ch < NCHUNK; ++ch)
        s += s_part[(size_t)ch * (BATCH * OO * EE) + g];

    // squared norm over the 16-element e axis (lanes g..g+15 share (b,o))
    float sq = s * s;
    #pragma unroll
    for (int m = 1; m < 16; m <<= 1) sq += __shfl_xor(sq, m, 16);

    float scale = sq / (1.f + sq) / (sqrtf(sq) + 1e-6f);
    float v = scale * s;

    if (last)       out[g] = v;
    else if (accum) V[g]  += v;
    else            V[g]   = v;
}

extern "C" void kernel_launch(void* const* d_in, const int* in_sizes, int n_in,
                              void* d_out, int out_size, void* d_ws, size_t ws_size,
                              hipStream_t stream) {
    const float* x = (const float*)d_in[0];   // [256,32,6,6,8]
    const float* W = (const float*)d_in[1];   // [1,32,6,6,10,8,16]
    float* out = (float*)d_out;               // [256,10,16]

    float* s_part = (float*)d_ws;                                   // NCHUNK*40960 floats
    float* V      = s_part + (size_t)NCHUNK * BATCH * OO * EE;      // 40960 floats

    dim3 grid(NCHUNK, NBT), blk(NT);
    const int sq_blocks = (BATCH * OO * EE) / 256;   // 160

    // iteration 1: b=0 -> c uniform 0.1; v1 -> V
    caps_pass_kernel<<<grid, blk, 0, stream>>>(x, W, V, s_part, 1);
    caps_squash_kernel<<<sq_blocks, 256, 0, stream>>>(s_part, V, out, 0, 0);
    // iteration 2: logits = dot(u_hat, v1); V += v2
    caps_pass_kernel<<<grid, blk, 0, stream>>>(x, W, V, s_part, 0);
    caps_squash_kernel<<<sq_blocks, 256, 0, stream>>>(s_part, V, out, 1, 0);
    // iteration 3 (final): logits = dot(u_hat, v1+v2); output v3
    caps_pass_kernel<<<grid, blk, 0, stream>>>(x, W, V, s_part, 0);
    caps_squash_kernel<<<sq_blocks, 256, 0, stream>>>(s_part, V, out, 0, 1);
}